// Round 7
// baseline (666.820 us; speedup 1.0000x reference)
//
#include <hip/hip_runtime.h>
#include <stdint.h>

#define BATCH 8192
#define DIM   1024            // elements per row; fp8 => also bytes per row
#define NTILE 64              // 8192 / 128 tiles per dimension
#define MAXB  292             // max tiles per XCD band
#define GRIDX (8 * MAXB)      // padded x-grid; blocks past band size exit

#define FSZ   ((size_t)BATCH * DIM)   // bytes per feature in Fn (8 MB)
#define PAN   ((size_t)64 * 8192)     // bytes per K-block panel: 64 rowblks x 8 KB
#define OPB   8192                    // bytes per operand tile image (128 rows x 64 kB)
#define SBUF  8192                    // bytes per LDS tile buffer

#define FSCALE 8.0f                          // pre-scale before fp8 quant
#define EXPF   (2.0f / (FSCALE * FSCALE))    // exp(2*dot) = exp(acc * EXPF)

typedef int   intx4    __attribute__((ext_vector_type(4)));
typedef int   intx8    __attribute__((ext_vector_type(8)));
typedef float floatx16 __attribute__((ext_vector_type(16)));

__device__ __forceinline__ void async_ld16(const void* g, void* l) {
    __builtin_amdgcn_global_load_lds(
        (__attribute__((address_space(1))) void*)(void*)g,
        (__attribute__((address_space(3))) void*)l,
        16, 0, 0);
}

// ------------- row L2-normalize: fp32 -> fp8 e4m3 (x FSCALE) -------------
// Output is FRAG-PACKED for the sim kernel's 32x32x64 MX-fp8 MFMA:
//   Fn[f][kb:16][rowblk:64][rowgrp:4][p:2][l:64][16 B]
// where lane l of a 32-row group holds row (l&31), k-bytes
// [(l>>5)*32, +32) of the 64-B K-block; p selects the 16-B half.
// (Generalizes the HW-verified 16x16x128 f8f6f4 mapping: lane l -> row
// l&(M-1), 32-B k-chunk l>>log2(M).)  Staging stays a pure linear copy and
// frag reads are lane-contiguous ds_read_b128 (conflict-free, no swizzle).
// ROUND-7: norm rewritten 32-rows-per-block so writes land as fully-covered
// 64-B lines (old per-row version scattered 4-B words at 256-B/512-KB
// strides -> ~4x write amplification, est. 40-60 us of the 90-us gap).
__global__ __launch_bounds__(256) void norm_kernel(const float* __restrict__ text,
                                                   const float* __restrict__ image,
                                                   unsigned char* __restrict__ out) {
    const int f = blockIdx.y;
    const float* in = f ? image : text;
    const int row0 = blockIdx.x * 32;         // 32-aligned row group
    const int t    = threadIdx.x;
    const int r32  = t >> 3;                  // row within group, 0..31
    const int sub  = t & 7;                   // 8 threads per row
    const int row  = row0 + r32;
    const float4* src = (const float4*)(in + (size_t)row * DIM);

    float4 v[32];
    float ss = 0.f;
    #pragma unroll
    for (int i = 0; i < 32; ++i) {            // fi = sub + 8i  (128-B runs/8 lanes)
        v[i] = src[sub + 8 * i];
        ss += v[i].x * v[i].x + v[i].y * v[i].y + v[i].z * v[i].z + v[i].w * v[i].w;
    }
    ss += __shfl_xor(ss, 1); ss += __shfl_xor(ss, 2); ss += __shfl_xor(ss, 4);
    const float inv = FSCALE / fmaxf(sqrtf(ss), 1e-12f);

    // element e = 4*(sub+8i): kb=i>>1, khi=i&1, p=sub>>2, byte b=(sub&3)*4,
    // lane l = khi*32 + r32.  Per wave per i: two dense 128-B output regions.
    const int rb     = row >> 7;
    const int rowgrp = (row >> 5) & 3;
    unsigned char* obase = out + (size_t)f * FSZ + (size_t)rb * OPB
                         + rowgrp * 2048 + (sub >> 2) * 1024 + (sub & 3) * 4;
    #pragma unroll
    for (int i = 0; i < 32; ++i) {
        int p = __builtin_amdgcn_cvt_pk_fp8_f32(v[i].x * inv, v[i].y * inv, 0, false);
        p     = __builtin_amdgcn_cvt_pk_fp8_f32(v[i].z * inv, v[i].w * inv, p, true);
        const int l = (i & 1) * 32 + r32;
        *(int*)(obase + (size_t)(i >> 1) * PAN + l * 16) = p;
    }
}

// -------- fused symmetric sim GEMM (MX-fp8 32x32x64) + exp + dual sum --------
// ROUND-7: MFMA switched 16x16x32 fp8 (2047 TF) -> mfma_scale_f32_32x32x64
// f8f6f4 with unit scales (4686 TF measured) at the SAME BK=64 / 32-KB-LDS /
// high-occupancy structure that round 6 proved out (MFMA pipe time per block
// halves: 8.1K -> 4.4K cyc/SIMD).  4 waves in 2x2; each wave owns 64x64 =
// 2x2 tiles of 32x32; 4 MFMAs + 8 ds_read_b128 per K-block.
// Epilogue uses the 32x32 C/D map: col=lane&31, row=(r&3)+8*(r>>2)+4*(lane>>5).
// NO global atomics: block (bi,bj) owns slot bj (row-parts) / bi (col-parts).
__global__ __launch_bounds__(256, 3) void sim_kernel(const unsigned char* __restrict__ F,
                                                     const int* __restrict__ label,
                                                     float* __restrict__ P) {
    // band tables: bj in [bs[x], be[x]); bn[x] = tiles in band
    const int bs[8] = {0, 23, 32, 40, 46, 51, 56, 60};
    const int be[8] = {23, 32, 40, 46, 51, 56, 60, 64};
    const int bn[8] = {276, 252, 292, 261, 245, 270, 234, 250};

    const int x = blockIdx.x & 7;       // XCD (round-robin dispatch heuristic)
    const int l = blockIdx.x >> 3;      // local index within band
    if (l >= bn[x]) return;             // padding block

    const int s = bs[x];
    const int w = be[x] - s;
    int bi, bj;
    const int nfull = s * w;
    if (l < nfull) {
        bi = l / w;
        bj = s + (l % w);
    } else {
        int l2 = l - nfull;
        int k = 0, width = w;
        while (l2 >= width) { l2 -= width; --width; ++k; }
        bi = s + k;
        bj = bi + l2;
    }
    const bool diag = (bi == bj);

    const int f = blockIdx.z;
    const int rowTile = bi * 128;
    const int colTile = bj * 128;

    // two 8-KB image buffers per operand (double buffer), linear layout.
    __shared__ __align__(16) unsigned char As[2][SBUF];
    __shared__ __align__(16) unsigned char Bs[2][SBUF];

    const int tid  = threadIdx.x;
    const int lane = tid & 63;
    const int wave = tid >> 6;
    const int wm   = wave >> 1;        // 2x2 wave grid over the 128x128 tile
    const int wn   = wave & 1;
    const int hi   = lane >> 5;
    const int c31  = lane & 31;

    // staging: per K-block each wave copies 2 KB of A and 2 KB of B
    // (2+2 global_load_lds of 1 KB contiguous each; pure linear copy).
    const unsigned char* gA = F + (size_t)f * FSZ + (size_t)bi * OPB + wave * 2048 + lane * 16;
    const unsigned char* gB = F + (size_t)f * FSZ + (size_t)bj * OPB + wave * 2048 + lane * 16;
    unsigned char* lA = As[0] + wave * 2048 + lane * 16;
    unsigned char* lB = Bs[0] + wave * 2048 + lane * 16;

    floatx16 acc[2][2];
    #pragma unroll
    for (int mi = 0; mi < 2; ++mi)
        #pragma unroll
        for (int ni = 0; ni < 2; ++ni)
            #pragma unroll
            for (int r = 0; r < 16; ++r) acc[mi][ni][r] = 0.f;

    // ---- prologue: stage K-block 0 into buffer 0 (4 loads/thread in flight) ----
    #pragma unroll
    for (int t = 0; t < 2; ++t) {
        async_ld16(gA + (size_t)t * 1024, lA + t * 1024);
        async_ld16(gB + (size_t)t * 1024, lB + t * 1024);
    }
    gA += PAN; gB += PAN;

    #pragma unroll
    for (int kb = 0; kb < 16; ++kb) {
        const int cur = kb & 1;
        const int nxt = cur ^ 1;
        if (kb < 15) {
            // prefetch K-block kb+1 into the buffer not read this iteration
            #pragma unroll
            for (int t = 0; t < 2; ++t) {
                async_ld16(gA + (size_t)t * 1024, lA + nxt * SBUF + t * 1024);
                async_ld16(gB + (size_t)t * 1024, lB + nxt * SBUF + t * 1024);
            }
            gA += PAN; gB += PAN;
            asm volatile("s_waitcnt vmcnt(4)" ::: "memory");   // this wave's kb loads
        } else {
            asm volatile("s_waitcnt vmcnt(0)" ::: "memory");
        }
        __builtin_amdgcn_s_barrier();        // all waves' kb data in LDS
        __builtin_amdgcn_sched_barrier(0);   // keep ds_reads below the barrier

        const unsigned char* aBase = As[cur];
        const unsigned char* bBase = Bs[cur];

        intx8 bfr[2];
        #pragma unroll
        for (int ni = 0; ni < 2; ++ni) {
            const unsigned char* r = bBase + (wn * 2 + ni) * 2048 + lane * 16;
            intx4 lo = *(const intx4*)r;
            intx4 h4 = *(const intx4*)(r + 1024);
            bfr[ni][0] = lo[0]; bfr[ni][1] = lo[1]; bfr[ni][2] = lo[2]; bfr[ni][3] = lo[3];
            bfr[ni][4] = h4[0]; bfr[ni][5] = h4[1]; bfr[ni][6] = h4[2]; bfr[ni][7] = h4[3];
        }
        __builtin_amdgcn_s_setprio(1);
        #pragma unroll
        for (int mi = 0; mi < 2; ++mi) {
            const unsigned char* r = aBase + (wm * 2 + mi) * 2048 + lane * 16;
            intx4 lo = *(const intx4*)r;
            intx4 h4 = *(const intx4*)(r + 1024);
            intx8 afr;
            afr[0] = lo[0]; afr[1] = lo[1]; afr[2] = lo[2]; afr[3] = lo[3];
            afr[4] = h4[0]; afr[5] = h4[1]; afr[6] = h4[2]; afr[7] = h4[3];
            acc[mi][0] = __builtin_amdgcn_mfma_scale_f32_32x32x64_f8f6f4(
                afr, bfr[0], acc[mi][0],
                0, 0,                     // cbsz=fp8(e4m3), blgp=fp8(e4m3)
                0, 0x7F7F7F7F,            // scale_a = 2^0
                0, 0x7F7F7F7F);           // scale_b = 2^0
            acc[mi][1] = __builtin_amdgcn_mfma_scale_f32_32x32x64_f8f6f4(
                afr, bfr[1], acc[mi][1],
                0, 0, 0, 0x7F7F7F7F, 0, 0x7F7F7F7F);
        }
        __builtin_amdgcn_s_setprio(0);
        __builtin_amdgcn_sched_barrier(0);   // keep reads/MFMA above the barrier
        __builtin_amdgcn_s_barrier();        // buf[cur] free for next prefetch
    }

    // ---- epilogue: e = exp(acc * EXPF), eye mask, block-local LDS
    //      reduction, then conflict-free partial-sum stores (no atomics) ----
    // 32x32 C/D: col = c31, row = (r&3) + 8*(r>>2) + 4*hi  (r = acc reg 0..15)
    __syncthreads();                      // all frag reads done; As reusable
    float* red = (float*)As;              // 4 KB needed, 16 KB available
    // layout (floats): [0..256)   rowR, indexed wn*128 + rowLoc
    //                  [256..512) rowN
    //                  [512..768) colR, indexed wm*128 + colLoc
    //                  [768..1024) colN
    // every entry written by exactly one lane -> plain ds_write, no init.

    int   colg[2], colLoc[2];
    float wRc[2];                        // col label weight (row-part bucket)
    #pragma unroll
    for (int ni = 0; ni < 2; ++ni) {
        colLoc[ni] = wn * 64 + ni * 32 + c31;
        colg[ni]   = colTile + colLoc[ni];
        wRc[ni]    = (label[colg[ni]] != 0) ? 1.0f : 0.0f;
    }

    float colR[2] = {0.f, 0.f};
    float colN[2] = {0.f, 0.f};

    #pragma unroll
    for (int mi = 0; mi < 2; ++mi) {
        #pragma unroll
        for (int r = 0; r < 16; ++r) {
            const int rowIn  = (r & 3) + 8 * (r >> 2) + 4 * hi;
            const int rowLoc = wm * 64 + mi * 32 + rowIn;
            const int rowg   = rowTile + rowLoc;
            const float wRr  = (label[rowg] != 0) ? 1.0f : 0.0f;
            float pR = 0.f, pN = 0.f;
            #pragma unroll
            for (int ni = 0; ni < 2; ++ni) {
                float c = acc[mi][ni][r];
                float e = __expf(c * EXPF);
                if (diag) e = (rowg == colg[ni]) ? 0.0f : e;      // eye mask
                pR += wRc[ni] * e;
                pN += (1.0f - wRc[ni]) * e;
                colR[ni] += wRr * e;
                colN[ni] += (1.0f - wRr) * e;
            }
            // reduce over the 32 cols held in this half-wave
            #pragma unroll
            for (int m = 1; m < 32; m <<= 1) {
                pR += __shfl_xor(pR, m);
                pN += __shfl_xor(pN, m);
            }
            if (c31 == 0) {               // one writer per (wave, mi, r, hi)
                red[wn * 128 + rowLoc]       = pR;
                red[256 + wn * 128 + rowLoc] = pN;
            }
        }
    }

    if (!diag) {
        #pragma unroll
        for (int ni = 0; ni < 2; ++ni) {
            float cR = colR[ni], cN = colN[ni];
            cR += __shfl_xor(cR, 32);     // add the other half's 32 rows
            cN += __shfl_xor(cN, 32);
            if (hi == 0) {
                red[512 + wm * 128 + colLoc[ni]] = cR;
                red[768 + wm * 128 + colLoc[ni]] = cN;
            }
        }
    }

    __syncthreads();
    // P layout: [f][u(R=0,N=1)][slot 0..63][g 0..8191]
    float* Pr = P + ((size_t)f * 2 + 0) * (size_t)NTILE * BATCH;
    float* Pn = P + ((size_t)f * 2 + 1) * (size_t)NTILE * BATCH;
    if (tid < 128) {
        Pr[(size_t)bj * BATCH + rowTile + tid] = red[tid]       + red[128 + tid];
        Pn[(size_t)bj * BATCH + rowTile + tid] = red[256 + tid] + red[384 + tid];
        if (!diag) {
            Pr[(size_t)bi * BATCH + colTile + tid] = red[512 + tid] + red[640 + tid];
            Pn[(size_t)bi * BATCH + colTile + tid] = red[768 + tid] + red[896 + tid];
        }
    }
}

// -------- final: 64-slot partial reduce + per-row loss + global reduce --------
__global__ __launch_bounds__(256) void loss_kernel(const float* __restrict__ P,
                                                   const int* __restrict__ label,
                                                   float* __restrict__ out) {
    const int idx = blockIdx.x * 256 + threadIdx.x;   // 0..16383 = (f, i)
    const int f = idx >> 13;
    const int i = idx & (BATCH - 1);
    const int lab = label[i];
    const float* Pr = P + ((size_t)f * 2 + 0) * (size_t)NTILE * BATCH;
    const float* Pn = Pr + (size_t)NTILE * BATCH;
    float sR = 0.f, sN = 0.f;
    #pragma unroll 8
    for (int s = 0; s < NTILE; ++s) {
        sR += Pr[(size_t)s * BATCH + i];
        sN += Pn[(size_t)s * BATCH + i];
    }
    const float own = lab ? sR : sN;
    const float oth = lab ? sN : sR;
    float t = -logf(own / (own + oth) + 1e-8f) * (1.0f / 4096.0f);
    #pragma unroll
    for (int m = 32; m >= 1; m >>= 1) t += __shfl_xor(t, m);
    __shared__ float red[4];
    if ((threadIdx.x & 63) == 0) red[threadIdx.x >> 6] = t;
    __syncthreads();
    if (threadIdx.x == 0) atomicAdd(out, red[0] + red[1] + red[2] + red[3]);
}

extern "C" void kernel_launch(void* const* d_in, const int* in_sizes, int n_in,
                              void* d_out, int out_size, void* d_ws, size_t ws_size,
                              hipStream_t stream) {
    const float* text  = (const float*)d_in[0];
    const float* image = (const float*)d_in[1];
    const int*   label = (const int*)d_in[2];
    float* out = (float*)d_out;

    // workspace: Fn[2][16][64rb][8KB] fp8 (16 MB), then P[2][2][64][8192] f32 (16 MB)
    unsigned char* Fn = (unsigned char*)d_ws;
    float* P = (float*)((char*)d_ws + (size_t)2 * BATCH * DIM);

    hipMemsetAsync(out, 0, sizeof(float), stream);

    dim3 ngrid(BATCH / 32, 2);
    norm_kernel<<<ngrid, 256, 0, stream>>>(text, image, Fn);

    dim3 grid(GRIDX, 1, 2);
    sim_kernel<<<grid, 256, 0, stream>>>(Fn, label, P);

    loss_kernel<<<(2 * BATCH) / 256, 256, 0, stream>>>(P, label, out);
}

// Round 9
// 216.858 us; speedup vs baseline: 3.0749x; 3.0749x over previous
//
#include <hip/hip_runtime.h>
#include <stdint.h>

#define BATCH 8192
#define DIM   1024            // elements per row; fp8 => also bytes per row
#define NTILE 64              // 8192 / 128 tiles per dimension
#define MAXB  292             // max tiles per XCD band
#define GRIDX (8 * MAXB)      // padded x-grid; blocks past band size exit

#define FSZ   ((size_t)BATCH * DIM)   // bytes per feature in Fn (8 MB)
#define PAN   ((size_t)64 * 8192)     // bytes per K-block panel: 64 rowblks x 8 KB
#define OPB   8192                    // bytes per operand tile image (128 rows x 64 kB)
#define SBUF  8192                    // bytes per LDS tile buffer

#define FSCALE 8.0f                          // pre-scale before fp8 quant
#define EXPF   (2.0f / (FSCALE * FSCALE))    // exp(2*dot) = exp(acc * EXPF)

typedef int   intx4   __attribute__((ext_vector_type(4)));
typedef float floatx4 __attribute__((ext_vector_type(4)));
typedef long  longx2  __attribute__((ext_vector_type(2)));

__device__ __forceinline__ void async_ld16(const void* g, void* l) {
    __builtin_amdgcn_global_load_lds(
        (__attribute__((address_space(1))) void*)(void*)g,
        (__attribute__((address_space(3))) void*)l,
        16, 0, 0);
}

__device__ __forceinline__ longx2 as_l2(intx4 v) {
    longx2 r;
    __builtin_memcpy(&r, &v, 16);
    return r;
}

// ------------- row L2-normalize: fp32 -> fp8 e4m3 (x FSCALE) -------------
// Output is FRAG-PACKED for the sim kernel's 16x16x32 fp8 MFMA (round-6
// layout, byte-identical):
//   Fn[f][kb:16][rowblk:64][ g:8 ][ q:4 ][ cl:16 ][16 B]
// chunk (row, kb, q) bytes = elements kb*64+q*8+[0..8) ++ kb*64+32+q*8+[0..8).
// ROUND-8/9: 32 rows/block, 8 threads/row; each thread writes whole 16-B int4
// chunks and a wave's stores tile complete 64-B lines (the round-6 norm wrote
// scattered 4-B words -> ~4x write amplification; norm was ~70 us vs 13 us
// roofline = the bulk of the 90-us non-sim gap).
__global__ __launch_bounds__(256) void norm_kernel(const float* __restrict__ text,
                                                   const float* __restrict__ image,
                                                   unsigned char* __restrict__ out) {
    const int f = blockIdx.y;
    const float* in = f ? image : text;
    const int row0 = blockIdx.x * 32;         // 32-aligned row group
    const int t    = threadIdx.x;
    const int r32  = t >> 3;                  // row within group, 0..31
    const int sub  = t & 7;                   // 8 threads per row
    const int row  = row0 + r32;
    const float4* src = (const float4*)(in + (size_t)row * DIM);

    const int q   = sub & 3;                  // chunk q owned by this thread
    const int kb0 = sub >> 2;                 // kb parity owned by this thread

    // thread covers fi = (kb0+2s)*16 + 2q + {0,1,8,9}, s=0..7  (bijective,
    // 8 subs x 32 float4 = the full 256-float4 row; reads dense per row)
    float4 v[8][4];
    float ss = 0.f;
    #pragma unroll
    for (int s = 0; s < 8; ++s) {
        const int fb = (kb0 + 2 * s) * 16 + 2 * q;
        v[s][0] = src[fb];
        v[s][1] = src[fb + 1];
        v[s][2] = src[fb + 8];
        v[s][3] = src[fb + 9];
        #pragma unroll
        for (int u = 0; u < 4; ++u)
            ss += v[s][u].x * v[s][u].x + v[s][u].y * v[s][u].y
                + v[s][u].z * v[s][u].z + v[s][u].w * v[s][u].w;
    }
    // reduce over the 8 subs of this row (lanes r32*8+sub: xor 1,2,4 stay in-row)
    ss += __shfl_xor(ss, 1); ss += __shfl_xor(ss, 2); ss += __shfl_xor(ss, 4);
    const float inv = FSCALE / fmaxf(sqrtf(ss), 1e-12f);

    const int rb = row >> 7;
    const int g  = (row & 127) >> 4;
    const int cl = row & 15;
    unsigned char* obase = out + (size_t)f * FSZ + (size_t)rb * OPB
                         + g * 1024 + q * 256 + cl * 16;
    #pragma unroll
    for (int s = 0; s < 8; ++s) {
        intx4 w;
        #pragma unroll
        for (int u = 0; u < 4; ++u) {         // u = (ks,j): (0,0),(0,1),(1,0),(1,1)
            int p = __builtin_amdgcn_cvt_pk_fp8_f32(v[s][u].x * inv, v[s][u].y * inv, 0, false);
            p     = __builtin_amdgcn_cvt_pk_fp8_f32(v[s][u].z * inv, v[s][u].w * inv, p, true);
            w[u] = p;
        }
        *(intx4*)(obase + (size_t)(kb0 + 2 * s) * PAN) = w;   // full 16-B chunk
    }
}

// -------- fused symmetric sim GEMM (fp8 K=32 MFMA) + exp + dual sum --------
// Byte-identical to the round-6 kernel (137 us, MfmaUtil 43%, VGPR 64,
// 0 bank conflicts, no spills). Round 7's mfma_scale_f32_32x32x64 (floatx16
// acc) was spilled to scratch by the allocator (VGPR_Count=84 < the 88
// needed; 1.2 GB scratch writes) -> 4.4x regression. The 16x16 family's
// floatx4 accumulators are the compiler-safe path.
// Epilogue: NO global atomics. Block (bi,bj) owns slot bj for row-partials and
// slot bi for col-partials -> exact disjoint cover of P[f][u][slot][g].
__global__ __launch_bounds__(256, 3) void sim_kernel(const unsigned char* __restrict__ F,
                                                     const int* __restrict__ label,
                                                     float* __restrict__ P) {
    // band tables: bj in [bs[x], be[x]); bn[x] = tiles in band
    const int bs[8] = {0, 23, 32, 40, 46, 51, 56, 60};
    const int be[8] = {23, 32, 40, 46, 51, 56, 60, 64};
    const int bn[8] = {276, 252, 292, 261, 245, 270, 234, 250};

    const int x = blockIdx.x & 7;       // XCD (round-robin dispatch heuristic)
    const int l = blockIdx.x >> 3;      // local index within band
    if (l >= bn[x]) return;             // padding block

    const int s = bs[x];
    const int w = be[x] - s;
    int bi, bj;
    const int nfull = s * w;
    if (l < nfull) {
        bi = l / w;
        bj = s + (l % w);
    } else {
        int l2 = l - nfull;
        int k = 0, width = w;
        while (l2 >= width) { l2 -= width; --width; ++k; }
        bi = s + k;
        bj = bi + l2;
    }
    const bool diag = (bi == bj);

    const int f = blockIdx.z;
    const int rowTile = bi * 128;
    const int colTile = bj * 128;

    // two 8-KB image buffers per operand (double buffer), linear layout.
    __shared__ __align__(16) unsigned char As[2][SBUF];
    __shared__ __align__(16) unsigned char Bs[2][SBUF];

    const int tid  = threadIdx.x;
    const int lane = tid & 63;
    const int wave = tid >> 6;
    const int wm   = wave >> 1;        // 2x2 wave grid over the 128x128 tile
    const int wn   = wave & 1;
    const int quad = lane >> 4;
    const int cl   = lane & 15;

    // staging: per K-block each wave copies 2 KB of A and 2 KB of B
    // (2+2 global_load_lds of 1 KB contiguous each; pure linear copy).
    const unsigned char* gA = F + (size_t)f * FSZ + (size_t)bi * OPB + wave * 2048 + lane * 16;
    const unsigned char* gB = F + (size_t)f * FSZ + (size_t)bj * OPB + wave * 2048 + lane * 16;
    unsigned char* lA = As[0] + wave * 2048 + lane * 16;
    unsigned char* lB = Bs[0] + wave * 2048 + lane * 16;

    floatx4 acc[4][4];
    const floatx4 z4 = {0.f, 0.f, 0.f, 0.f};
    #pragma unroll
    for (int mi = 0; mi < 4; ++mi)
        #pragma unroll
        for (int ni = 0; ni < 4; ++ni) acc[mi][ni] = z4;

    // frag read base: lane (q,cl) reads b128 at group*1024 + q*256 + cl*16;
    // the 16 B = (k-lo 8 B || k-hi 8 B) for the two K=32 MFMA steps.
    const unsigned char* aF = As[0] + quad * 256 + cl * 16;
    const unsigned char* bF = Bs[0] + quad * 256 + cl * 16;

    // ---- prologue: stage K-block 0 into buffer 0 (4 loads/wave in flight) ----
    #pragma unroll
    for (int t = 0; t < 2; ++t) {
        async_ld16(gA + (size_t)t * 1024, lA + t * 1024);
        async_ld16(gB + (size_t)t * 1024, lB + t * 1024);
    }
    gA += PAN; gB += PAN;

    #pragma unroll
    for (int kb = 0; kb < 16; ++kb) {
        const int cur = kb & 1;
        const int nxt = cur ^ 1;
        if (kb < 15) {
            // prefetch K-block kb+1 into the buffer not read this iteration
            #pragma unroll
            for (int t = 0; t < 2; ++t) {
                async_ld16(gA + (size_t)t * 1024, lA + nxt * SBUF + t * 1024);
                async_ld16(gB + (size_t)t * 1024, lB + nxt * SBUF + t * 1024);
            }
            gA += PAN; gB += PAN;
            asm volatile("s_waitcnt vmcnt(4)" ::: "memory");   // this wave's kb loads
        } else {
            asm volatile("s_waitcnt vmcnt(0)" ::: "memory");
        }
        __builtin_amdgcn_s_barrier();        // all waves' kb data in LDS
        __builtin_amdgcn_sched_barrier(0);   // keep ds_reads below the barrier

        longx2 bfr[4];
        #pragma unroll
        for (int ni = 0; ni < 4; ++ni)
            bfr[ni] = as_l2(*(const intx4*)(bF + cur * SBUF + (wn * 4 + ni) * 1024));
        __builtin_amdgcn_s_setprio(1);
        #pragma unroll
        for (int mi = 0; mi < 4; ++mi) {
            longx2 afr = as_l2(*(const intx4*)(aF + cur * SBUF + (wm * 4 + mi) * 1024));
            #pragma unroll
            for (int ni = 0; ni < 4; ++ni) {
                acc[mi][ni] = __builtin_amdgcn_mfma_f32_16x16x32_fp8_fp8(
                    afr[0], bfr[ni][0], acc[mi][ni], 0, 0, 0);
                acc[mi][ni] = __builtin_amdgcn_mfma_f32_16x16x32_fp8_fp8(
                    afr[1], bfr[ni][1], acc[mi][ni], 0, 0, 0);
            }
        }
        __builtin_amdgcn_s_setprio(0);
        __builtin_amdgcn_sched_barrier(0);   // keep reads/MFMA above the barrier
        __builtin_amdgcn_s_barrier();        // buf[cur] free for next prefetch
    }

    // ---- epilogue: e = exp(acc * EXPF), eye mask, block-local LDS
    //      reduction, then conflict-free partial-sum stores (no atomics) ----
    __syncthreads();                      // all frag reads done; As reusable
    float* red = (float*)As;              // 4 KB needed, 16 KB available
    // layout (floats): [0..256)   rowR, indexed wn*128 + rowLoc
    //                  [256..512) rowN
    //                  [512..768) colR, indexed wm*128 + colLoc
    //                  [768..1024) colN
    // every entry written by exactly one lane -> plain ds_write, no init.

    int   colg[4], colLoc[4];
    float wRc[4];                        // col label weight (row-part bucket)
    #pragma unroll
    for (int ni = 0; ni < 4; ++ni) {
        colLoc[ni] = wn * 64 + ni * 16 + cl;
        colg[ni]   = colTile + colLoc[ni];
        wRc[ni]    = (label[colg[ni]] != 0) ? 1.0f : 0.0f;
    }

    float colR[4] = {0.f, 0.f, 0.f, 0.f};
    float colN[4] = {0.f, 0.f, 0.f, 0.f};

    #pragma unroll
    for (int mi = 0; mi < 4; ++mi) {
        const int rowLocB = wm * 64 + mi * 16 + quad * 4;   // C/D: row=quad*4+reg
        #pragma unroll
        for (int r = 0; r < 4; ++r) {
            const int rowLoc = rowLocB + r;
            const int rowg   = rowTile + rowLoc;
            const float wRr  = (label[rowg] != 0) ? 1.0f : 0.0f;
            float pR = 0.f, pN = 0.f;
            #pragma unroll
            for (int ni = 0; ni < 4; ++ni) {
                float c = acc[mi][ni][r];
                float e = __expf(c * EXPF);
                if (diag) e = (rowg == colg[ni]) ? 0.0f : e;      // eye mask
                pR += wRc[ni] * e;
                pN += (1.0f - wRc[ni]) * e;
                colR[ni] += wRr * e;
                colN[ni] += (1.0f - wRr) * e;
            }
            #pragma unroll
            for (int m = 1; m < 16; m <<= 1) {
                pR += __shfl_xor(pR, m);
                pN += __shfl_xor(pN, m);
            }
            if (cl == 0) {
                red[wn * 128 + rowLoc]       = pR;
                red[256 + wn * 128 + rowLoc] = pN;
            }
        }
    }

    if (!diag) {
        #pragma unroll
        for (int ni = 0; ni < 4; ++ni) {
            float cR = colR[ni], cN = colN[ni];
            cR += __shfl_xor(cR, 16); cN += __shfl_xor(cN, 16);
            cR += __shfl_xor(cR, 32); cN += __shfl_xor(cN, 32);
            if (quad == 0) {
                red[512 + wm * 128 + colLoc[ni]] = cR;
                red[768 + wm * 128 + colLoc[ni]] = cN;
            }
        }
    }

    __syncthreads();
    // P layout: [f][u(R=0,N=1)][slot 0..63][g 0..8191]
    float* Pr = P + ((size_t)f * 2 + 0) * (size_t)NTILE * BATCH;
    float* Pn = P + ((size_t)f * 2 + 1) * (size_t)NTILE * BATCH;
    if (tid < 128) {
        Pr[(size_t)bj * BATCH + rowTile + tid] = red[tid]       + red[128 + tid];
        Pn[(size_t)bj * BATCH + rowTile + tid] = red[256 + tid] + red[384 + tid];
        if (!diag) {
            Pr[(size_t)bi * BATCH + colTile + tid] = red[512 + tid] + red[640 + tid];
            Pn[(size_t)bi * BATCH + colTile + tid] = red[768 + tid] + red[896 + tid];
        }
    }
}

// -------- final: 64-slot partial reduce + per-row loss + global reduce --------
__global__ __launch_bounds__(256) void loss_kernel(const float* __restrict__ P,
                                                   const int* __restrict__ label,
                                                   float* __restrict__ out) {
    const int idx = blockIdx.x * 256 + threadIdx.x;   // 0..16383 = (f, i)
    const int f = idx >> 13;
    const int i = idx & (BATCH - 1);
    const int lab = label[i];
    const float* Pr = P + ((size_t)f * 2 + 0) * (size_t)NTILE * BATCH;
    const float* Pn = Pr + (size_t)NTILE * BATCH;
    float sR = 0.f, sN = 0.f;
    #pragma unroll 8
    for (int s = 0; s < NTILE; ++s) {
        sR += Pr[(size_t)s * BATCH + i];
        sN += Pn[(size_t)s * BATCH + i];
    }
    const float own = lab ? sR : sN;
    const float oth = lab ? sN : sR;
    float t = -logf(own / (own + oth) + 1e-8f) * (1.0f / 4096.0f);
    #pragma unroll
    for (int m = 32; m >= 1; m >>= 1) t += __shfl_xor(t, m);
    __shared__ float red[4];
    if ((threadIdx.x & 63) == 0) red[threadIdx.x >> 6] = t;
    __syncthreads();
    if (threadIdx.x == 0) atomicAdd(out, red[0] + red[1] + red[2] + red[3]);
}

extern "C" void kernel_launch(void* const* d_in, const int* in_sizes, int n_in,
                              void* d_out, int out_size, void* d_ws, size_t ws_size,
                              hipStream_t stream) {
    const float* text  = (const float*)d_in[0];
    const float* image = (const float*)d_in[1];
    const int*   label = (const int*)d_in[2];
    float* out = (float*)d_out;

    // workspace: Fn[2][16][64rb][8KB] fp8 (16 MB), then P[2][2][64][8192] f32 (16 MB)
    unsigned char* Fn = (unsigned char*)d_ws;
    float* P = (float*)((char*)d_ws + (size_t)2 * BATCH * DIM);

    hipMemsetAsync(out, 0, sizeof(float), stream);

    dim3 ngrid(BATCH / 32, 2);
    norm_kernel<<<ngrid, 256, 0, stream>>>(text, image, Fn);

    dim3 grid(GRIDX, 1, 2);
    sim_kernel<<<grid, 256, 0, stream>>>(Fn, label, P);

    loss_kernel<<<(2 * BATCH) / 256, 256, 0, stream>>>(P, label, out);
}